// Round 6
// baseline (315.269 us; speedup 1.0000x reference)
//
#include <hip/hip_runtime.h>
#include <stdint.h>

typedef unsigned short ushort_t;
typedef unsigned int   uint_t;
typedef __attribute__((ext_vector_type(8))) short bf16x8;
typedef __attribute__((ext_vector_type(4))) float f32x4;

__device__ __forceinline__ float b2f(ushort_t u) {
    return __uint_as_float(((uint_t)u) << 16);
}
// fp32 -> bf16 round-to-nearest-even
__device__ __forceinline__ ushort_t f2b_rne(float f) {
    uint_t u = __float_as_uint(f);
    uint_t r = (u + 0x7FFFu + ((u >> 16) & 1u)) >> 16;
    return (ushort_t)r;
}
__device__ __forceinline__ float lrelu(float s) {
    return s >= 0.f ? s : 0.2f * s;
}

// ---------------------------------------------------------------------------
// SESSION NOTE: inputs are FP32 (R4 forensics). MFMA path runs fp32 inputs
// via hi/lo bf16 split: h ~= x_hi*W_hi + x_lo*W_hi + x_hi*W_lo (err ~2^-17).
// R5 measured 189 µs @ 44% occupancy, issue-util ~38% -> latency-bound.
// R6: (a) launch_bounds(256,6) — fp32 fallback branch is gone, kernel is 60
// VGPR, fits the ~85-reg budget; 6 blocks/CU. (b) per-row softmax weights
// computed once per (row,head) and parked in a_sv/a_dv (wS = 1-wU-wD),
// removing ~400 duplicated VALU cycles/thread from the epilogue.
// ---------------------------------------------------------------------------

// Prep: W [256k][256n] -> Wt planes in workspace, transposed to [n][k] bf16.
// plane 0 (offset 0): hi;  plane 1 (offset 65536): lo (fp32 && use_lo).
__global__ __launch_bounds__(256)
void wprep(const void* __restrict__ Win, const void* __restrict__ xin,
           ushort_t* __restrict__ Wt, int use_lo)
{
    __shared__ ushort_t th[64][72];   // +8 pad
    __shared__ ushort_t tl[64][72];
    __shared__ int flag;
    const int t = threadIdx.x;

    // dtype probe: bf16-pair storage -> low half-word exponent in [100,150]
    if (t < 64) {
        uint_t wv = ((const uint_t*)xin)[t];
        int elo   = (int)((wv >> 7) & 0xFFu);
        int pred  = (elo >= 100 && elo <= 150) ? 1 : 0;
        unsigned long long m = __ballot(pred);
        if (t == 0) flag = (__popcll(m) >= 40) ? 1 : 0;
    }
    __syncthreads();

    const int bi = blockIdx.x >> 2, bj = blockIdx.x & 3;
    const int k0 = bi * 64, n0 = bj * 64;
    const int r = t >> 6, c = t & 63;

    if (flag) {
        const ushort_t* W = (const ushort_t*)Win;
#pragma unroll
        for (int i = 0; i < 16; ++i)
            th[i * 4 + r][c] = W[(size_t)(k0 + i * 4 + r) * 256 + n0 + c];
        __syncthreads();
#pragma unroll
        for (int i = 0; i < 16; ++i)
            Wt[(size_t)(n0 + i * 4 + r) * 256 + k0 + c] = th[c][i * 4 + r];
    } else {
        const float* W = (const float*)Win;
#pragma unroll
        for (int i = 0; i < 16; ++i) {
            float f = W[(size_t)(k0 + i * 4 + r) * 256 + n0 + c];
            ushort_t h = f2b_rne(f);
            th[i * 4 + r][c] = h;
            tl[i * 4 + r][c] = f2b_rne(f - b2f(h));
        }
        __syncthreads();
#pragma unroll
        for (int i = 0; i < 16; ++i) {
            Wt[(size_t)(n0 + i * 4 + r) * 256 + k0 + c] = th[c][i * 4 + r];
            if (use_lo)
                Wt[65536 + (size_t)(n0 + i * 4 + r) * 256 + k0 + c] =
                    tl[c][i * 4 + r];
        }
    }
}

// ---------------------------------------------------------------------------
// Main: 1 graph/block (grid 4096), 4 waves = 4 heads. MFMA GEMM h = x·W
// (M=24 in 2 tiles of 16; N=64/wave; K=256 = 8 steps). fp32 inputs use the
// hi/lo split (6 MFMA/nt/ks); bf16 inputs hi only. a_s/a_d from accumulators
// via 16-lane shfl_xor; softmax weights precomputed per (row,head);
// epilogue = 2 LDS broadcasts + 3 FMA per output.
// LDS 26.1 KB -> 6 blocks/CU; launch_bounds(256,6): ~85-reg cap, no spill
// (kernel is 60 VGPR; the reg-fat fp32 branch was removed in R5).
// ---------------------------------------------------------------------------
__global__ __launch_bounds__(256, 6)
void gat_mfma(const void* __restrict__ xin,
              const void* __restrict__ asin,
              const void* __restrict__ adin,
              const void* __restrict__ biin,
              const int*  __restrict__ ei,
              const ushort_t* __restrict__ Wt,
              float*      __restrict__ out,
              int E0, int use_lo)
{
    // union: x_hi [24][264] + x_lo [24][264] bf16 (25.3 KB) / h fp32 [24][257]
    __shared__ __align__(16) float hx_s[6336];   // 25,344 B
    __shared__ float a_sv[24 * 4], a_dv[24 * 4]; // a-logits, then wU/wD
    __shared__ int has_up[24], has_dn[24];
    __shared__ int flag_sm;

    const int t = threadIdx.x;
    const int g = blockIdx.x;

    if (t < 64) {
        uint_t wv = ((const uint_t*)xin)[t];
        int elo   = (int)((wv >> 7) & 0xFFu);
        int pred  = (elo >= 100 && elo <= 150) ? 1 : 0;
        unsigned long long m = __ballot(pred);
        if (t == 0) flag_sm = (__popcll(m) >= 40) ? 1 : 0;
    }
    if (t < 24) { has_up[t] = 0; has_dn[t] = 0; }
    __syncthreads();

    // edge parse (robust to int32 / int64 storage)
    {
        const int e64 = (ei[1] == 0 && ei[3] == 0 && ei[5] == 0) ? 1 : 0;
        if (t < E0) {
            int s, d;
            if (e64) { s = ei[2 * t];  d = ei[2 * E0 + 2 * t]; }
            else     { s = ei[t];      d = ei[E0 + t]; }
            if (s == d - 1) has_up[d] = 1;
            if (s == d + 1) has_dn[d] = 1;
        }
    }
    const int isbf16 = flag_sm;

    const int w  = t >> 6;              // wave == head
    const int l  = t & 63;
    const int lr = l & 15;
    const int lk = l >> 4;

    ushort_t* xh = (ushort_t*)hx_s;     // [24][264]
    ushort_t* xl = xh + 24 * 264;       // [24][264] (fp32+use_lo mode only)

    // ---- stage x into LDS as bf16 (hi, and lo residual for fp32 inputs)
    if (isbf16) {
        const ushort_t* xg = (const ushort_t*)xin + (size_t)g * 6144;
#pragma unroll
        for (int i = 0; i < 3; ++i) {
            int c = i * 256 + t, row = c >> 5, ch = c & 31;
            *(uint4*)(xh + row * 264 + ch * 8) =
                *(const uint4*)(xg + row * 256 + ch * 8);
        }
    } else {
        const float* xg = (const float*)xin + (size_t)g * 6144;
#pragma unroll
        for (int i = 0; i < 3; ++i) {
            int c = i * 256 + t, row = c >> 5, ch = c & 31;
            const float* src = xg + row * 256 + ch * 8;
            float4 f0 = *(const float4*)(src);
            float4 f1 = *(const float4*)(src + 4);
            ushort4 h0, h1;
            h0.x = f2b_rne(f0.x); h0.y = f2b_rne(f0.y);
            h0.z = f2b_rne(f0.z); h0.w = f2b_rne(f0.w);
            h1.x = f2b_rne(f1.x); h1.y = f2b_rne(f1.y);
            h1.z = f2b_rne(f1.z); h1.w = f2b_rne(f1.w);
            *(ushort4*)(xh + row * 264 + ch * 8)     = h0;
            *(ushort4*)(xh + row * 264 + ch * 8 + 4) = h1;
            if (use_lo) {
                ushort4 l0, l1;
                l0.x = f2b_rne(f0.x - b2f(h0.x));
                l0.y = f2b_rne(f0.y - b2f(h0.y));
                l0.z = f2b_rne(f0.z - b2f(h0.z));
                l0.w = f2b_rne(f0.w - b2f(h0.w));
                l1.x = f2b_rne(f1.x - b2f(h1.x));
                l1.y = f2b_rne(f1.y - b2f(h1.y));
                l1.z = f2b_rne(f1.z - b2f(h1.z));
                l1.w = f2b_rne(f1.w - b2f(h1.w));
                *(ushort4*)(xl + row * 264 + ch * 8)     = l0;
                *(ushort4*)(xl + row * 264 + ch * 8 + 4) = l1;
            }
        }
    }
    __syncthreads();

    // ---- MFMA GEMM: 2 M-tiles x 4 N-tiles x 8 K-steps
    f32x4 acc[2][4];
#pragma unroll
    for (int mt = 0; mt < 2; ++mt)
#pragma unroll
        for (int nt = 0; nt < 4; ++nt) {
            f32x4 z = {0.f, 0.f, 0.f, 0.f};
            acc[mt][nt] = z;
        }

    // m-tile 1 rows 16..31: lanes lr>=8 would read rows 24..31 (outputs
    // discarded) — clamp the READ row to 23 to stay in-bounds of the union.
    const int r1 = (lr < 8) ? (16 + lr) : 23;
    const ushort_t* xa0h = xh + lr * 264 + lk * 8;
    const ushort_t* xa1h = xh + r1 * 264 + lk * 8;
    const ushort_t* wbh  = Wt + (size_t)(w * 64 + lr) * 256 + lk * 8;

    const int lo_on = (!isbf16) && use_lo;
    if (lo_on) {
        const ushort_t* xa0l = xa0h + 24 * 264;
        const ushort_t* xa1l = xa1h + 24 * 264;
        const ushort_t* wbl  = wbh + 65536;
#pragma unroll
        for (int ks = 0; ks < 8; ++ks) {
            bf16x8 a0h = *(const bf16x8*)(xa0h + ks * 32);
            bf16x8 a1h = *(const bf16x8*)(xa1h + ks * 32);
            bf16x8 a0l = *(const bf16x8*)(xa0l + ks * 32);
            bf16x8 a1l = *(const bf16x8*)(xa1l + ks * 32);
#pragma unroll
            for (int nt = 0; nt < 4; ++nt) {
                bf16x8 bh = *(const bf16x8*)(wbh + nt * 4096 + ks * 32);
                bf16x8 bl = *(const bf16x8*)(wbl + nt * 4096 + ks * 32);
                acc[0][nt] = __builtin_amdgcn_mfma_f32_16x16x32_bf16(
                    a0h, bh, acc[0][nt], 0, 0, 0);
                acc[0][nt] = __builtin_amdgcn_mfma_f32_16x16x32_bf16(
                    a0l, bh, acc[0][nt], 0, 0, 0);
                acc[0][nt] = __builtin_amdgcn_mfma_f32_16x16x32_bf16(
                    a0h, bl, acc[0][nt], 0, 0, 0);
                acc[1][nt] = __builtin_amdgcn_mfma_f32_16x16x32_bf16(
                    a1h, bh, acc[1][nt], 0, 0, 0);
                acc[1][nt] = __builtin_amdgcn_mfma_f32_16x16x32_bf16(
                    a1l, bh, acc[1][nt], 0, 0, 0);
                acc[1][nt] = __builtin_amdgcn_mfma_f32_16x16x32_bf16(
                    a1h, bl, acc[1][nt], 0, 0, 0);
            }
        }
    } else {
#pragma unroll
        for (int ks = 0; ks < 8; ++ks) {
            bf16x8 a0h = *(const bf16x8*)(xa0h + ks * 32);
            bf16x8 a1h = *(const bf16x8*)(xa1h + ks * 32);
#pragma unroll
            for (int nt = 0; nt < 4; ++nt) {
                bf16x8 bh = *(const bf16x8*)(wbh + nt * 4096 + ks * 32);
                acc[0][nt] = __builtin_amdgcn_mfma_f32_16x16x32_bf16(
                    a0h, bh, acc[0][nt], 0, 0, 0);
                acc[1][nt] = __builtin_amdgcn_mfma_f32_16x16x32_bf16(
                    a1h, bh, acc[1][nt], 0, 0, 0);
            }
        }
    }
    __syncthreads();    // all waves done reading x planes; h aliases below

    // ---- a_s/a_d from accumulators: per-lane partial over its 4 cols,
    //      then 16-lane butterfly (lanes differ only in lr)
    float as_c[4], ad_c[4];
#pragma unroll
    for (int nt = 0; nt < 4; ++nt) {
        const int idx = w * 64 + nt * 16 + lr;
        if (isbf16) {
            as_c[nt] = b2f(((const ushort_t*)asin)[idx]);
            ad_c[nt] = b2f(((const ushort_t*)adin)[idx]);
        } else {
            as_c[nt] = ((const float*)asin)[idx];
            ad_c[nt] = ((const float*)adin)[idx];
        }
    }
#pragma unroll
    for (int mt = 0; mt < 2; ++mt)
#pragma unroll
        for (int r = 0; r < 4; ++r) {
            float ps = acc[mt][0][r] * as_c[0] + acc[mt][1][r] * as_c[1]
                     + acc[mt][2][r] * as_c[2] + acc[mt][3][r] * as_c[3];
            float pd = acc[mt][0][r] * ad_c[0] + acc[mt][1][r] * ad_c[1]
                     + acc[mt][2][r] * ad_c[2] + acc[mt][3][r] * ad_c[3];
#pragma unroll
            for (int s = 1; s < 16; s <<= 1) {
                ps += __shfl_xor(ps, s);
                pd += __shfl_xor(pd, s);
            }
            const int row = mt * 16 + lk * 4 + r;
            if (lr == 0 && row < 24) {
                a_sv[row * 4 + w] = ps;
                a_dv[row * 4 + w] = pd;
            }
        }

    // ---- h fragments -> LDS fp32 [24][257] (own-wave columns only)
    float* h_s = hx_s;
#pragma unroll
    for (int mt = 0; mt < 2; ++mt) {
        const int r0 = mt * 16 + lk * 4;
#pragma unroll
        for (int nt = 0; nt < 4; ++nt) {
            const int col = w * 64 + nt * 16 + lr;
#pragma unroll
            for (int r = 0; r < 4; ++r)
                if (r0 + r < 24) h_s[(r0 + r) * 257 + col] = acc[mt][nt][r];
        }
    }

    // ---- per-(row,head) softmax weights, computed ONCE per wave by lanes
    // l<24, then parked back into a_sv (wU) / a_dv (wD); wS = 1-wU-wD.
    // Own-wave LDS only. All lanes' a_sv reads precede the overwrite in
    // program order (lockstep wave), so no hazard.
    if (l < 24) {
        const int j = l;
        const float ad = a_dv[j * 4 + w];
        const float aS = a_sv[j * 4 + w];
        const float aU = (j > 0)  ? a_sv[(j - 1) * 4 + w] : 0.f;
        const float aD = (j < 23) ? a_sv[(j + 1) * 4 + w] : 0.f;
        const bool hu = has_up[j] != 0;
        const bool hd = has_dn[j] != 0;
        const float sU = hu ? lrelu(aU + ad) : -1e30f;
        const float sS =      lrelu(aS + ad);
        const float sD = hd ? lrelu(aD + ad) : -1e30f;
        const float mx = fmaxf(sS, fmaxf(sU, sD));
        const float eU = __expf(sU - mx);
        const float eS = __expf(sS - mx);
        const float eD = __expf(sD - mx);
        const float inv = 1.f / (eU + eS + eD);
        a_sv[j * 4 + w] = eU * inv;     // wU
        a_dv[j * 4 + w] = eD * inv;     // wD
    }

    // ---- epilogue: out = bias + wU*h_prv + wS*h_cur + wD*h_nxt
    const float bias_v = isbf16 ? b2f(((const ushort_t*)biin)[t])
                                : ((const float*)biin)[t];
    float* og = out + (size_t)g * 6144 + t;
    float h_prv = 0.f;
    float h_cur = h_s[t];
#pragma unroll
    for (int j = 0; j < 24; ++j) {
        const float h_nxt = (j < 23) ? h_s[(j + 1) * 257 + t] : 0.f;
        const float wU = a_sv[j * 4 + w];      // LDS broadcast (all lanes same)
        const float wD = a_dv[j * 4 + w];
        const float wS = 1.f - wU - wD;
        og[j * 256] = bias_v + wU * h_prv + wS * h_cur + wD * h_nxt;
        h_prv = h_cur; h_cur = h_nxt;
    }
}

// ---------------------------------------------------------------------------
// Baseline kernel kept verbatim as fallback for tiny/absent workspace.
// ---------------------------------------------------------------------------
__global__ __launch_bounds__(256)
void gat_base(const void* __restrict__ xin, const void* __restrict__ Win,
              const void* __restrict__ asin, const void* __restrict__ adin,
              const void* __restrict__ biin, const int* __restrict__ ei,
              float* __restrict__ out, int E0)
{
    __shared__ __align__(16) float x_f[24 * 256];
    __shared__ int has_up[24], has_dn[24];
    __shared__ int flag_sm;

    const int t = threadIdx.x;
    const int g = blockIdx.x;

    if (t < 64) {
        uint_t wv  = ((const uint_t*)xin)[t];
        int elo    = (int)((wv >> 7) & 0xFFu);
        int pred   = (elo >= 100 && elo <= 150) ? 1 : 0;
        unsigned long long m = __ballot(pred);
        if (t == 0) flag_sm = (__popcll(m) >= 40) ? 1 : 0;
    }
    if (t < 24) { has_up[t] = 0; has_dn[t] = 0; }
    __syncthreads();

    {
        const int e64 = (ei[1] == 0 && ei[3] == 0 && ei[5] == 0) ? 1 : 0;
        if (t < E0) {
            int s, d;
            if (e64) { s = ei[2 * t];  d = ei[2 * E0 + 2 * t]; }
            else     { s = ei[t];      d = ei[E0 + t]; }
            if (s == d - 1) has_up[d] = 1;
            if (s == d + 1) has_dn[d] = 1;
        }
    }
    const int isbf16 = flag_sm;

    if (isbf16) {
        const ushort_t* xg = (const ushort_t*)xin + (size_t)g * 6144;
#pragma unroll
        for (int i = 0; i < 6; ++i) {
            int c = i * 256 + t, row = c >> 6, off = (c & 63) * 4;
            ushort4 v = *(const ushort4*)&xg[row * 256 + off];
            float4 f;
            f.x = b2f(v.x); f.y = b2f(v.y); f.z = b2f(v.z); f.w = b2f(v.w);
            *(float4*)&x_f[row * 256 + off] = f;
        }
    } else {
        const float* xg = (const float*)xin + (size_t)g * 6144;
#pragma unroll
        for (int i = 0; i < 6; ++i) {
            int c = i * 256 + t, row = c >> 6, off = (c & 63) * 4;
            *(float4*)&x_f[row * 256 + off] = *(const float4*)&xg[row * 256 + off];
        }
    }
    __syncthreads();

    float acc[24];
#pragma unroll
    for (int j = 0; j < 24; ++j) acc[j] = 0.f;

    if (isbf16) {
        const ushort_t* Wp = (const ushort_t*)Win;
        for (int kc = 0; kc < 64; ++kc) {
            float w0 = b2f(Wp[(kc * 4 + 0) * 256 + t]);
            float w1 = b2f(Wp[(kc * 4 + 1) * 256 + t]);
            float w2 = b2f(Wp[(kc * 4 + 2) * 256 + t]);
            float w3 = b2f(Wp[(kc * 4 + 3) * 256 + t]);
#pragma unroll
            for (int j = 0; j < 24; ++j) {
                float4 xv = *(const float4*)&x_f[j * 256 + kc * 4];
                acc[j] += xv.x * w0 + xv.y * w1 + xv.z * w2 + xv.w * w3;
            }
        }
    } else {
        const float* Wp = (const float*)Win;
        for (int kc = 0; kc < 64; ++kc) {
            float w0 = Wp[(kc * 4 + 0) * 256 + t];
            float w1 = Wp[(kc * 4 + 1) * 256 + t];
            float w2 = Wp[(kc * 4 + 2) * 256 + t];
            float w3 = Wp[(kc * 4 + 3) * 256 + t];
#pragma unroll
            for (int j = 0; j < 24; ++j) {
                float4 xv = *(const float4*)&x_f[j * 256 + kc * 4];
                acc[j] += xv.x * w0 + xv.y * w1 + xv.z * w2 + xv.w * w3;
            }
        }
    }

    float att_sv, att_dv, bias_v;
    if (isbf16) {
        att_sv = b2f(((const ushort_t*)asin)[t]);
        att_dv = b2f(((const ushort_t*)adin)[t]);
        bias_v = b2f(((const ushort_t*)biin)[t]);
    } else {
        att_sv = ((const float*)asin)[t];
        att_dv = ((const float*)adin)[t];
        bias_v = ((const float*)biin)[t];
    }

    float asv[24], adv[24];
#pragma unroll
    for (int j = 0; j < 24; ++j) {
        float ps = acc[j] * att_sv;
        float pd = acc[j] * att_dv;
#pragma unroll
        for (int s = 1; s < 64; s <<= 1) {
            ps += __shfl_xor(ps, s);
            pd += __shfl_xor(pd, s);
        }
        asv[j] = ps;
        adv[j] = pd;
    }

    float* og = out + (size_t)g * 6144 + t;
#pragma unroll
    for (int j = 0; j < 24; ++j) {
        const bool hu = has_up[j] != 0;
        const bool hd = has_dn[j] != 0;
        const float ad = adv[j];
        const float aU = (j > 0)  ? asv[j - 1] : 0.f;
        const float aD = (j < 23) ? asv[j + 1] : 0.f;
        const float sU = hu ? lrelu(aU + ad) : -1e30f;
        const float sS =      lrelu(asv[j] + ad);
        const float sD = hd ? lrelu(aD + ad) : -1e30f;
        const float mx = fmaxf(sS, fmaxf(sU, sD));
        const float eU = __expf(sU - mx);
        const float eS = __expf(sS - mx);
        const float eD = __expf(sD - mx);
        const float inv = 1.f / (eU + eS + eD);
        const float hm = (j > 0)  ? acc[j - 1] : 0.f;
        const float hp = (j < 23) ? acc[j + 1] : 0.f;
        og[j * 256] = bias_v + inv * (eU * hm + eS * acc[j] + eD * hp);
    }
}

extern "C" void kernel_launch(void* const* d_in, const int* in_sizes, int n_in,
                              void* d_out, int out_size, void* d_ws, size_t ws_size,
                              hipStream_t stream) {
    (void)n_in; (void)out_size;
    const void* x  = d_in[0];
    const void* W  = d_in[1];
    const void* as = d_in[2];
    const void* ad = d_in[3];
    const void* bi = d_in[4];
    const int*  ei = (const int*)d_in[5];
    float*      o  = (float*)d_out;

    const int n5 = in_sizes[5];
    const int E0 = (n5 == 184) ? 46 : n5 / 2;   // 46 directed edges
    const int G  = in_sizes[0] / 6144;          // 4096 graphs

    const size_t PLANE = (size_t)65536 * sizeof(ushort_t);   // 128 KB
    if (ws_size >= 2 * PLANE) {
        hipLaunchKernelGGL(wprep, dim3(16), dim3(256), 0, stream,
                           W, x, (ushort_t*)d_ws, 1);
        hipLaunchKernelGGL(gat_mfma, dim3(G), dim3(256), 0, stream,
                           x, as, ad, bi, ei, (const ushort_t*)d_ws, o, E0, 1);
    } else if (ws_size >= PLANE) {
        hipLaunchKernelGGL(wprep, dim3(16), dim3(256), 0, stream,
                           W, x, (ushort_t*)d_ws, 0);
        hipLaunchKernelGGL(gat_mfma, dim3(G), dim3(256), 0, stream,
                           x, as, ad, bi, ei, (const ushort_t*)d_ws, o, E0, 0);
    } else {
        hipLaunchKernelGGL(gat_base, dim3(G), dim3(256), 0, stream,
                           x, W, as, ad, bi, ei, o, E0);
    }
}

// Round 7
// 296.014 us; speedup vs baseline: 1.0650x; 1.0650x over previous
//
#include <hip/hip_runtime.h>
#include <stdint.h>

typedef unsigned short ushort_t;
typedef unsigned int   uint_t;
typedef __attribute__((ext_vector_type(8))) short bf16x8;
typedef __attribute__((ext_vector_type(4))) float f32x4;

__device__ __forceinline__ float b2f(ushort_t u) {
    return __uint_as_float(((uint_t)u) << 16);
}
// fp32 -> bf16 round-to-nearest-even
__device__ __forceinline__ ushort_t f2b_rne(float f) {
    uint_t u = __float_as_uint(f);
    uint_t r = (u + 0x7FFFu + ((u >> 16) & 1u)) >> 16;
    return (ushort_t)r;
}
__device__ __forceinline__ float lrelu(float s) {
    return s >= 0.f ? s : 0.2f * s;
}

// ---------------------------------------------------------------------------
// SESSION NOTE: inputs are FP32 (R4 forensics). MFMA path runs fp32 inputs
// via hi/lo bf16 split: h ~= x_hi*W_hi + x_lo*W_hi + x_hi*W_lo (err ~2^-17).
// R6 lesson: launch_bounds(256,6) -> ~85-reg unified cap -> spills
// (+24MB WRITE / +11MB FETCH) that cancelled the epilogue win. The kernel is
// latency-bound at ~4 B/cy/CU (Little's law, ~2-3 B-loads in flight).
// R7: (a) (256,4) = spill-free 128-reg budget (R5-proven);
//     (b) nt-major GEMM with 8-deep B-load bursts -> ~8 loads in flight.
// ---------------------------------------------------------------------------

// Prep: W [256k][256n] -> Wt planes in workspace, transposed to [n][k] bf16.
// plane 0 (offset 0): hi;  plane 1 (offset 65536): lo (fp32 && use_lo).
__global__ __launch_bounds__(256)
void wprep(const void* __restrict__ Win, const void* __restrict__ xin,
           ushort_t* __restrict__ Wt, int use_lo)
{
    __shared__ ushort_t th[64][72];   // +8 pad
    __shared__ ushort_t tl[64][72];
    __shared__ int flag;
    const int t = threadIdx.x;

    // dtype probe: bf16-pair storage -> low half-word exponent in [100,150]
    if (t < 64) {
        uint_t wv = ((const uint_t*)xin)[t];
        int elo   = (int)((wv >> 7) & 0xFFu);
        int pred  = (elo >= 100 && elo <= 150) ? 1 : 0;
        unsigned long long m = __ballot(pred);
        if (t == 0) flag = (__popcll(m) >= 40) ? 1 : 0;
    }
    __syncthreads();

    const int bi = blockIdx.x >> 2, bj = blockIdx.x & 3;
    const int k0 = bi * 64, n0 = bj * 64;
    const int r = t >> 6, c = t & 63;

    if (flag) {
        const ushort_t* W = (const ushort_t*)Win;
#pragma unroll
        for (int i = 0; i < 16; ++i)
            th[i * 4 + r][c] = W[(size_t)(k0 + i * 4 + r) * 256 + n0 + c];
        __syncthreads();
#pragma unroll
        for (int i = 0; i < 16; ++i)
            Wt[(size_t)(n0 + i * 4 + r) * 256 + k0 + c] = th[c][i * 4 + r];
    } else {
        const float* W = (const float*)Win;
#pragma unroll
        for (int i = 0; i < 16; ++i) {
            float f = W[(size_t)(k0 + i * 4 + r) * 256 + n0 + c];
            ushort_t h = f2b_rne(f);
            th[i * 4 + r][c] = h;
            tl[i * 4 + r][c] = f2b_rne(f - b2f(h));
        }
        __syncthreads();
#pragma unroll
        for (int i = 0; i < 16; ++i) {
            Wt[(size_t)(n0 + i * 4 + r) * 256 + k0 + c] = th[c][i * 4 + r];
            if (use_lo)
                Wt[65536 + (size_t)(n0 + i * 4 + r) * 256 + k0 + c] =
                    tl[c][i * 4 + r];
        }
    }
}

// ---------------------------------------------------------------------------
// Main: 1 graph/block (grid 4096), 4 waves = 4 heads. MFMA GEMM h = x·W
// (M=24 in 2 tiles of 16; N=64/wave in 4 nt-tiles; K=256 = 8 ks-steps).
// nt-major loop: per nt, burst-load 8 B-frags (hi), run 4 MFMAs/ks reusing
// each A-frag for hi+lo products, then burst the 8 lo B-frags into the same
// registers and finish with 2 MFMAs/ks. ~8 global loads in flight per wave.
// Softmax weights precomputed per (row,head); epilogue = 2 LDS broadcasts
// + 3 FMA per output. launch_bounds(256,4): 128-reg unified budget, no
// spill (R5-proven); LDS 26.1 KB.
// ---------------------------------------------------------------------------
__global__ __launch_bounds__(256, 4)
void gat_mfma(const void* __restrict__ xin,
              const void* __restrict__ asin,
              const void* __restrict__ adin,
              const void* __restrict__ biin,
              const int*  __restrict__ ei,
              const ushort_t* __restrict__ Wt,
              float*      __restrict__ out,
              int E0, int use_lo)
{
    // union: x_hi [24][264] + x_lo [24][264] bf16 (25.3 KB) / h fp32 [24][257]
    __shared__ __align__(16) float hx_s[6336];   // 25,344 B
    __shared__ float a_sv[24 * 4], a_dv[24 * 4]; // a-logits, then wU/wD
    __shared__ int has_up[24], has_dn[24];
    __shared__ int flag_sm;

    const int t = threadIdx.x;
    const int g = blockIdx.x;

    if (t < 64) {
        uint_t wv = ((const uint_t*)xin)[t];
        int elo   = (int)((wv >> 7) & 0xFFu);
        int pred  = (elo >= 100 && elo <= 150) ? 1 : 0;
        unsigned long long m = __ballot(pred);
        if (t == 0) flag_sm = (__popcll(m) >= 40) ? 1 : 0;
    }
    if (t < 24) { has_up[t] = 0; has_dn[t] = 0; }
    __syncthreads();

    // edge parse (robust to int32 / int64 storage)
    {
        const int e64 = (ei[1] == 0 && ei[3] == 0 && ei[5] == 0) ? 1 : 0;
        if (t < E0) {
            int s, d;
            if (e64) { s = ei[2 * t];  d = ei[2 * E0 + 2 * t]; }
            else     { s = ei[t];      d = ei[E0 + t]; }
            if (s == d - 1) has_up[d] = 1;
            if (s == d + 1) has_dn[d] = 1;
        }
    }
    const int isbf16 = flag_sm;

    const int w  = t >> 6;              // wave == head
    const int l  = t & 63;
    const int lr = l & 15;
    const int lk = l >> 4;

    ushort_t* xh = (ushort_t*)hx_s;     // [24][264]
    ushort_t* xl = xh + 24 * 264;       // [24][264] (fp32+use_lo mode only)

    // ---- stage x into LDS as bf16 (hi, and lo residual for fp32 inputs)
    if (isbf16) {
        const ushort_t* xg = (const ushort_t*)xin + (size_t)g * 6144;
#pragma unroll
        for (int i = 0; i < 3; ++i) {
            int c = i * 256 + t, row = c >> 5, ch = c & 31;
            *(uint4*)(xh + row * 264 + ch * 8) =
                *(const uint4*)(xg + row * 256 + ch * 8);
        }
    } else {
        const float* xg = (const float*)xin + (size_t)g * 6144;
#pragma unroll
        for (int i = 0; i < 3; ++i) {
            int c = i * 256 + t, row = c >> 5, ch = c & 31;
            const float* src = xg + row * 256 + ch * 8;
            float4 f0 = *(const float4*)(src);
            float4 f1 = *(const float4*)(src + 4);
            ushort4 h0, h1;
            h0.x = f2b_rne(f0.x); h0.y = f2b_rne(f0.y);
            h0.z = f2b_rne(f0.z); h0.w = f2b_rne(f0.w);
            h1.x = f2b_rne(f1.x); h1.y = f2b_rne(f1.y);
            h1.z = f2b_rne(f1.z); h1.w = f2b_rne(f1.w);
            *(ushort4*)(xh + row * 264 + ch * 8)     = h0;
            *(ushort4*)(xh + row * 264 + ch * 8 + 4) = h1;
            if (use_lo) {
                ushort4 l0, l1;
                l0.x = f2b_rne(f0.x - b2f(h0.x));
                l0.y = f2b_rne(f0.y - b2f(h0.y));
                l0.z = f2b_rne(f0.z - b2f(h0.z));
                l0.w = f2b_rne(f0.w - b2f(h0.w));
                l1.x = f2b_rne(f1.x - b2f(h1.x));
                l1.y = f2b_rne(f1.y - b2f(h1.y));
                l1.z = f2b_rne(f1.z - b2f(h1.z));
                l1.w = f2b_rne(f1.w - b2f(h1.w));
                *(ushort4*)(xl + row * 264 + ch * 8)     = l0;
                *(ushort4*)(xl + row * 264 + ch * 8 + 4) = l1;
            }
        }
    }
    __syncthreads();

    // ---- MFMA GEMM: nt-major, 8-deep B bursts
    f32x4 acc[2][4];
#pragma unroll
    for (int mt = 0; mt < 2; ++mt)
#pragma unroll
        for (int nt = 0; nt < 4; ++nt) {
            f32x4 z = {0.f, 0.f, 0.f, 0.f};
            acc[mt][nt] = z;
        }

    // m-tile 1 rows 16..31: lanes lr>=8 would read rows 24..31 (outputs
    // discarded) — clamp the READ row to 23 to stay in-bounds of the union.
    const int r1 = (lr < 8) ? (16 + lr) : 23;
    const ushort_t* xa0h = xh + lr * 264 + lk * 8;
    const ushort_t* xa1h = xh + r1 * 264 + lk * 8;
    const ushort_t* xa0l = xa0h + 24 * 264;
    const ushort_t* xa1l = xa1h + 24 * 264;

    const int lo_on = (!isbf16) && use_lo;
#pragma unroll
    for (int nt = 0; nt < 4; ++nt) {
        const ushort_t* wb = Wt + (size_t)(w * 64 + nt * 16 + lr) * 256 + lk * 8;
        bf16x8 bb[8];
        // burst: 8 hi-plane B-frags in flight
#pragma unroll
        for (int ks = 0; ks < 8; ++ks)
            bb[ks] = *(const bf16x8*)(wb + ks * 32);
        if (lo_on) {
#pragma unroll
            for (int ks = 0; ks < 8; ++ks) {
                bf16x8 a0h = *(const bf16x8*)(xa0h + ks * 32);
                bf16x8 a1h = *(const bf16x8*)(xa1h + ks * 32);
                bf16x8 a0l = *(const bf16x8*)(xa0l + ks * 32);
                bf16x8 a1l = *(const bf16x8*)(xa1l + ks * 32);
                acc[0][nt] = __builtin_amdgcn_mfma_f32_16x16x32_bf16(
                    a0h, bb[ks], acc[0][nt], 0, 0, 0);
                acc[1][nt] = __builtin_amdgcn_mfma_f32_16x16x32_bf16(
                    a1h, bb[ks], acc[1][nt], 0, 0, 0);
                acc[0][nt] = __builtin_amdgcn_mfma_f32_16x16x32_bf16(
                    a0l, bb[ks], acc[0][nt], 0, 0, 0);
                acc[1][nt] = __builtin_amdgcn_mfma_f32_16x16x32_bf16(
                    a1l, bb[ks], acc[1][nt], 0, 0, 0);
            }
            // burst: 8 lo-plane B-frags (reuse registers)
#pragma unroll
            for (int ks = 0; ks < 8; ++ks)
                bb[ks] = *(const bf16x8*)(wb + 65536 + ks * 32);
#pragma unroll
            for (int ks = 0; ks < 8; ++ks) {
                bf16x8 a0h = *(const bf16x8*)(xa0h + ks * 32);
                bf16x8 a1h = *(const bf16x8*)(xa1h + ks * 32);
                acc[0][nt] = __builtin_amdgcn_mfma_f32_16x16x32_bf16(
                    a0h, bb[ks], acc[0][nt], 0, 0, 0);
                acc[1][nt] = __builtin_amdgcn_mfma_f32_16x16x32_bf16(
                    a1h, bb[ks], acc[1][nt], 0, 0, 0);
            }
        } else {
#pragma unroll
            for (int ks = 0; ks < 8; ++ks) {
                bf16x8 a0h = *(const bf16x8*)(xa0h + ks * 32);
                bf16x8 a1h = *(const bf16x8*)(xa1h + ks * 32);
                acc[0][nt] = __builtin_amdgcn_mfma_f32_16x16x32_bf16(
                    a0h, bb[ks], acc[0][nt], 0, 0, 0);
                acc[1][nt] = __builtin_amdgcn_mfma_f32_16x16x32_bf16(
                    a1h, bb[ks], acc[1][nt], 0, 0, 0);
            }
        }
    }
    __syncthreads();    // all waves done reading x planes; h aliases below

    // ---- a_s/a_d from accumulators: per-lane partial over its 4 cols,
    //      then 16-lane butterfly (lanes differ only in lr)
    float as_c[4], ad_c[4];
#pragma unroll
    for (int nt = 0; nt < 4; ++nt) {
        const int idx = w * 64 + nt * 16 + lr;
        if (isbf16) {
            as_c[nt] = b2f(((const ushort_t*)asin)[idx]);
            ad_c[nt] = b2f(((const ushort_t*)adin)[idx]);
        } else {
            as_c[nt] = ((const float*)asin)[idx];
            ad_c[nt] = ((const float*)adin)[idx];
        }
    }
#pragma unroll
    for (int mt = 0; mt < 2; ++mt)
#pragma unroll
        for (int r = 0; r < 4; ++r) {
            float ps = acc[mt][0][r] * as_c[0] + acc[mt][1][r] * as_c[1]
                     + acc[mt][2][r] * as_c[2] + acc[mt][3][r] * as_c[3];
            float pd = acc[mt][0][r] * ad_c[0] + acc[mt][1][r] * ad_c[1]
                     + acc[mt][2][r] * ad_c[2] + acc[mt][3][r] * ad_c[3];
#pragma unroll
            for (int s = 1; s < 16; s <<= 1) {
                ps += __shfl_xor(ps, s);
                pd += __shfl_xor(pd, s);
            }
            const int row = mt * 16 + lk * 4 + r;
            if (lr == 0 && row < 24) {
                a_sv[row * 4 + w] = ps;
                a_dv[row * 4 + w] = pd;
            }
        }

    // ---- h fragments -> LDS fp32 [24][257] (own-wave columns only)
    float* h_s = hx_s;
#pragma unroll
    for (int mt = 0; mt < 2; ++mt) {
        const int r0 = mt * 16 + lk * 4;
#pragma unroll
        for (int nt = 0; nt < 4; ++nt) {
            const int col = w * 64 + nt * 16 + lr;
#pragma unroll
            for (int r = 0; r < 4; ++r)
                if (r0 + r < 24) h_s[(r0 + r) * 257 + col] = acc[mt][nt][r];
        }
    }

    // ---- per-(row,head) softmax weights, computed ONCE per wave by lanes
    // l<24, then parked back into a_sv (wU) / a_dv (wD); wS = 1-wU-wD.
    // Own-wave LDS only; same-wave ds ops are in program order -> no hazard.
    if (l < 24) {
        const int j = l;
        const float ad = a_dv[j * 4 + w];
        const float aS = a_sv[j * 4 + w];
        const float aU = (j > 0)  ? a_sv[(j - 1) * 4 + w] : 0.f;
        const float aD = (j < 23) ? a_sv[(j + 1) * 4 + w] : 0.f;
        const bool hu = has_up[j] != 0;
        const bool hd = has_dn[j] != 0;
        const float sU = hu ? lrelu(aU + ad) : -1e30f;
        const float sS =      lrelu(aS + ad);
        const float sD = hd ? lrelu(aD + ad) : -1e30f;
        const float mx = fmaxf(sS, fmaxf(sU, sD));
        const float eU = __expf(sU - mx);
        const float eS = __expf(sS - mx);
        const float eD = __expf(sD - mx);
        const float inv = 1.f / (eU + eS + eD);
        a_sv[j * 4 + w] = eU * inv;     // wU
        a_dv[j * 4 + w] = eD * inv;     // wD
    }

    // ---- epilogue: out = bias + wU*h_prv + wS*h_cur + wD*h_nxt
    const float bias_v = isbf16 ? b2f(((const ushort_t*)biin)[t])
                                : ((const float*)biin)[t];
    float* og = out + (size_t)g * 6144 + t;
    float h_prv = 0.f;
    float h_cur = h_s[t];
#pragma unroll
    for (int j = 0; j < 24; ++j) {
        const float h_nxt = (j < 23) ? h_s[(j + 1) * 257 + t] : 0.f;
        const float wU = a_sv[j * 4 + w];      // LDS broadcast (all lanes same)
        const float wD = a_dv[j * 4 + w];
        const float wS = 1.f - wU - wD;
        og[j * 256] = bias_v + wU * h_prv + wS * h_cur + wD * h_nxt;
        h_prv = h_cur; h_cur = h_nxt;
    }
}

// ---------------------------------------------------------------------------
// Baseline kernel kept verbatim as fallback for tiny/absent workspace.
// ---------------------------------------------------------------------------
__global__ __launch_bounds__(256)
void gat_base(const void* __restrict__ xin, const void* __restrict__ Win,
              const void* __restrict__ asin, const void* __restrict__ adin,
              const void* __restrict__ biin, const int* __restrict__ ei,
              float* __restrict__ out, int E0)
{
    __shared__ __align__(16) float x_f[24 * 256];
    __shared__ int has_up[24], has_dn[24];
    __shared__ int flag_sm;

    const int t = threadIdx.x;
    const int g = blockIdx.x;

    if (t < 64) {
        uint_t wv  = ((const uint_t*)xin)[t];
        int elo    = (int)((wv >> 7) & 0xFFu);
        int pred   = (elo >= 100 && elo <= 150) ? 1 : 0;
        unsigned long long m = __ballot(pred);
        if (t == 0) flag_sm = (__popcll(m) >= 40) ? 1 : 0;
    }
    if (t < 24) { has_up[t] = 0; has_dn[t] = 0; }
    __syncthreads();

    {
        const int e64 = (ei[1] == 0 && ei[3] == 0 && ei[5] == 0) ? 1 : 0;
        if (t < E0) {
            int s, d;
            if (e64) { s = ei[2 * t];  d = ei[2 * E0 + 2 * t]; }
            else     { s = ei[t];      d = ei[E0 + t]; }
            if (s == d - 1) has_up[d] = 1;
            if (s == d + 1) has_dn[d] = 1;
        }
    }
    const int isbf16 = flag_sm;

    if (isbf16) {
        const ushort_t* xg = (const ushort_t*)xin + (size_t)g * 6144;
#pragma unroll
        for (int i = 0; i < 6; ++i) {
            int c = i * 256 + t, row = c >> 6, off = (c & 63) * 4;
            ushort4 v = *(const ushort4*)&xg[row * 256 + off];
            float4 f;
            f.x = b2f(v.x); f.y = b2f(v.y); f.z = b2f(v.z); f.w = b2f(v.w);
            *(float4*)&x_f[row * 256 + off] = f;
        }
    } else {
        const float* xg = (const float*)xin + (size_t)g * 6144;
#pragma unroll
        for (int i = 0; i < 6; ++i) {
            int c = i * 256 + t, row = c >> 6, off = (c & 63) * 4;
            *(float4*)&x_f[row * 256 + off] = *(const float4*)&xg[row * 256 + off];
        }
    }
    __syncthreads();

    float acc[24];
#pragma unroll
    for (int j = 0; j < 24; ++j) acc[j] = 0.f;

    if (isbf16) {
        const ushort_t* Wp = (const ushort_t*)Win;
        for (int kc = 0; kc < 64; ++kc) {
            float w0 = b2f(Wp[(kc * 4 + 0) * 256 + t]);
            float w1 = b2f(Wp[(kc * 4 + 1) * 256 + t]);
            float w2 = b2f(Wp[(kc * 4 + 2) * 256 + t]);
            float w3 = b2f(Wp[(kc * 4 + 3) * 256 + t]);
#pragma unroll
            for (int j = 0; j < 24; ++j) {
                float4 xv = *(const float4*)&x_f[j * 256 + kc * 4];
                acc[j] += xv.x * w0 + xv.y * w1 + xv.z * w2 + xv.w * w3;
            }
        }
    } else {
        const float* Wp = (const float*)Win;
        for (int kc = 0; kc < 64; ++kc) {
            float w0 = Wp[(kc * 4 + 0) * 256 + t];
            float w1 = Wp[(kc * 4 + 1) * 256 + t];
            float w2 = Wp[(kc * 4 + 2) * 256 + t];
            float w3 = Wp[(kc * 4 + 3) * 256 + t];
#pragma unroll
            for (int j = 0; j < 24; ++j) {
                float4 xv = *(const float4*)&x_f[j * 256 + kc * 4];
                acc[j] += xv.x * w0 + xv.y * w1 + xv.z * w2 + xv.w * w3;
            }
        }
    }

    float att_sv, att_dv, bias_v;
    if (isbf16) {
        att_sv = b2f(((const ushort_t*)asin)[t]);
        att_dv = b2f(((const ushort_t*)adin)[t]);
        bias_v = b2f(((const ushort_t*)biin)[t]);
    } else {
        att_sv = ((const float*)asin)[t];
        att_dv = ((const float*)adin)[t];
        bias_v = ((const float*)biin)[t];
    }

    float asv[24], adv[24];
#pragma unroll
    for (int j = 0; j < 24; ++j) {
        float ps = acc[j] * att_sv;
        float pd = acc[j] * att_dv;
#pragma unroll
        for (int s = 1; s < 64; s <<= 1) {
            ps += __shfl_xor(ps, s);
            pd += __shfl_xor(pd, s);
        }
        asv[j] = ps;
        adv[j] = pd;
    }

    float* og = out + (size_t)g * 6144 + t;
#pragma unroll
    for (int j = 0; j < 24; ++j) {
        const bool hu = has_up[j] != 0;
        const bool hd = has_dn[j] != 0;
        const float ad = adv[j];
        const float aU = (j > 0)  ? asv[j - 1] : 0.f;
        const float aD = (j < 23) ? asv[j + 1] : 0.f;
        const float sU = hu ? lrelu(aU + ad) : -1e30f;
        const float sS =      lrelu(asv[j] + ad);
        const float sD = hd ? lrelu(aD + ad) : -1e30f;
        const float mx = fmaxf(sS, fmaxf(sU, sD));
        const float eU = __expf(sU - mx);
        const float eS = __expf(sS - mx);
        const float eD = __expf(sD - mx);
        const float inv = 1.f / (eU + eS + eD);
        const float hm = (j > 0)  ? acc[j - 1] : 0.f;
        const float hp = (j < 23) ? acc[j + 1] : 0.f;
        og[j * 256] = bias_v + inv * (eU * hm + eS * acc[j] + eD * hp);
    }
}

extern "C" void kernel_launch(void* const* d_in, const int* in_sizes, int n_in,
                              void* d_out, int out_size, void* d_ws, size_t ws_size,
                              hipStream_t stream) {
    (void)n_in; (void)out_size;
    const void* x  = d_in[0];
    const void* W  = d_in[1];
    const void* as = d_in[2];
    const void* ad = d_in[3];
    const void* bi = d_in[4];
    const int*  ei = (const int*)d_in[5];
    float*      o  = (float*)d_out;

    const int n5 = in_sizes[5];
    const int E0 = (n5 == 184) ? 46 : n5 / 2;   // 46 directed edges
    const int G  = in_sizes[0] / 6144;          // 4096 graphs

    const size_t PLANE = (size_t)65536 * sizeof(ushort_t);   // 128 KB
    if (ws_size >= 2 * PLANE) {
        hipLaunchKernelGGL(wprep, dim3(16), dim3(256), 0, stream,
                           W, x, (ushort_t*)d_ws, 1);
        hipLaunchKernelGGL(gat_mfma, dim3(G), dim3(256), 0, stream,
                           x, as, ad, bi, ei, (const ushort_t*)d_ws, o, E0, 1);
    } else if (ws_size >= PLANE) {
        hipLaunchKernelGGL(wprep, dim3(16), dim3(256), 0, stream,
                           W, x, (ushort_t*)d_ws, 0);
        hipLaunchKernelGGL(gat_mfma, dim3(G), dim3(256), 0, stream,
                           x, as, ad, bi, ei, (const ushort_t*)d_ws, o, E0, 0);
    } else {
        hipLaunchKernelGGL(gat_base, dim3(G), dim3(256), 0, stream,
                           x, W, as, ad, bi, ei, o, E0);
    }
}